// Round 11
// baseline (41.254 us; speedup 1.0000x reference)
//
#include <hip/hip_runtime.h>

// B=2, N=512, C_IN=16, C_OUT=16, HID=64
#define NQ   512
#define CI   16
#define CO   16
#define HIDN 64

typedef __attribute__((ext_vector_type(8))) short bf16x8;
typedef __attribute__((ext_vector_type(4))) float f32x4;
typedef __attribute__((ext_vector_type(2))) float f32x2;

// packed bf16 convert: low16 = bf16(a), high16 = bf16(b)
__device__ __forceinline__ unsigned cvt_pk_bf16(float a, float b) {
    unsigned r;
    asm("v_cvt_pk_bf16_f32 %0, %1, %2" : "=v"(r) : "v"(a), "v"(b));
    return r;
}
__device__ __forceinline__ unsigned short f32_to_bf16_rne(float v) {
    unsigned u = __builtin_bit_cast(unsigned, v);
    u += 0x7fffu + ((u >> 16) & 1u);
    return (unsigned short)(u >> 16);
}

// ---------------------------------------------------------------------------
// Kernel 1 (r4-proven, verbatim): per zb
//   Mbf[zb][part][i][k] : bf16 hi/lo split of M[i][k] = sum_j f[j]*W2[(i*16+j)*64+k]
//   Cws[zb][i]          : sum_j f[j]*b2[i*16+j]
// ---------------------------------------------------------------------------
__global__ __launch_bounds__(256) void compute_M_kernel(
    const float* __restrict__ features,   // [1024,16]
    const float* __restrict__ W2,         // [256,64]
    const float* __restrict__ b2,         // [256]
    unsigned short* __restrict__ Mbf,     // [1024][2][16][64]
    float* __restrict__ Cws)              // [1024][16]
{
    const int zb  = blockIdx.x;
    const int tid = threadIdx.x;

    float f[CI];
    #pragma unroll
    for (int j = 0; j < CI; ++j) f[j] = features[zb * CI + j];

    #pragma unroll
    for (int e = 0; e < 4; ++e) {
        int idx = tid + e * 256;        // 0..1023 = i*64 + k
        int i   = idx >> 6;
        int k   = idx & 63;
        float acc = 0.f;
        #pragma unroll
        for (int j = 0; j < CI; ++j)
            acc = fmaf(f[j], W2[(i * CI + j) * HIDN + k], acc);
        unsigned short hi = f32_to_bf16_rne(acc);
        float hf = __builtin_bit_cast(float, (unsigned)hi << 16);
        unsigned short lo = f32_to_bf16_rne(acc - hf);
        Mbf[(size_t)zb * 2048 + idx]        = hi;
        Mbf[(size_t)zb * 2048 + 1024 + idx] = lo;
    }
    if (tid < CO) {
        float acc = 0.f;
        #pragma unroll
        for (int j = 0; j < CI; ++j)
            acc = fmaf(f[j], b2[tid * CI + j], acc);
        Cws[zb * CO + tid] = acc;
    }
}

// ---------------------------------------------------------------------------
// Kernel 2: 512 blocks = z(2) x a_tile(32 of 16a) x b_tile(8 of 64b).
// 512 threads = 8 waves; wave wv owns (16 a) x (8 b), loops b.
// Per b: Af = M[b] hi/lo fragments (global, L2-hit); hv built in B-frag
// layout; 4 MFMA; result f32x4 -> per-wave LDS transpose buffer.
// Flush: 16 stores, each PERFECTLY CONTIGUOUS 512B (lane l covers bytes
// 8l..8l+7 of one (a, b-range) output row). No __syncthreads anywhere.
// LDS strides: b-plane 306 dwords, a-row 18 dwords (conflicts <=4-5 way).
// ---------------------------------------------------------------------------
__global__ __launch_bounds__(512, 4) void apply_transpose_kernel(
    const float* __restrict__ geometry,        // [1024,3]
    const float* __restrict__ W1,              // [64,4]
    const float* __restrict__ b1,              // [64]
    const unsigned short* __restrict__ Mbf,    // [1024][2][16][64]
    const float* __restrict__ Cws,             // [1024][16]
    float* __restrict__ out)                   // [2,512,512,16]
{
    __shared__ float tbuf[8 * 8 * 306];   // 8 waves x 2448 dwords = 78.3 KB

    const int bid  = blockIdx.x;
    const int z    = bid >> 8;           // 0..1
    const int a_t  = (bid >> 3) & 31;    // 32 a-tiles
    const int b_t  = bid & 7;            // 8 b-tiles (fastest -> XCD-local M slice)
    const int tid  = threadIdx.x;
    const int wv   = tid >> 6;
    const int lane = tid & 63;
    const int col  = lane & 15;          // = i for A-frag (M), = a-offset for B-frag (hv)
    const int g    = lane >> 4;

    const int a0 = a_t * 16;
    const int bq = b_t * 64 + wv * 8;    // wave's 8-b range

    float* wbuf = tbuf + wv * (8 * 306); // wave-private

    // per-lane 'a' geometry (fixed for the whole wave lifetime)
    const float* ga = geometry + (size_t)(z * NQ + a0 + col) * 3;
    const float gax = ga[0], gay = ga[1], gaz = ga[2];

    // hoist b1 slice for this lane's h-values
    float bb[16];
    #pragma unroll
    for (int kc = 0; kc < 2; ++kc)
        #pragma unroll
        for (int j = 0; j < 8; ++j)
            bb[kc * 8 + j] = b1[kc * 32 + g * 8 + j];

    #pragma unroll 1
    for (int bl = 0; bl < 8; ++bl) {
        const int b = bq + bl;
        // wave-uniform b -> scalar loads
        const float gbx = geometry[(z * NQ + b) * 3 + 0];
        const float gby = geometry[(z * NQ + b) * 3 + 1];
        const float gbz = geometry[(z * NQ + b) * 3 + 2];
        const float rx = gbx - gax, ry = gby - gay, rz = gbz - gaz;
        const float nrm = sqrtf(fmaf(rx, rx, fmaf(ry, ry, rz * rz)) + 1e-12f);

        // A-frags: M[b] hi/lo (global, L2-resident; 16B per-lane loads)
        const unsigned short* Mzb = Mbf + (size_t)(z * NQ + b) * 2048;
        bf16x8 Af[2][2];   // [part][kc]
        #pragma unroll
        for (int part = 0; part < 2; ++part)
            #pragma unroll
            for (int kc = 0; kc < 2; ++kc)
                Af[part][kc] = *reinterpret_cast<const bf16x8*>(
                    Mzb + part * 1024 + col * 64 + kc * 32 + g * 8);

        // accumulator init: lane (col,g) holds D^T rows i=g*4+r, col a=col
        f32x4 acc = *reinterpret_cast<const f32x4*>(Cws + (z * NQ + b) * CO + g * 4);

        #pragma unroll
        for (int kc = 0; kc < 2; ++kc) {
            float hv[8];
            #pragma unroll
            for (int j = 0; j < 8; ++j) {
                const int h = kc * 32 + g * 8 + j;
                const f32x4 w = *reinterpret_cast<const f32x4*>(W1 + h * 4);
                float x = bb[kc * 8 + j];
                x = fmaf(rx,  w[0], x);
                x = fmaf(ry,  w[1], x);
                x = fmaf(rz,  w[2], x);
                x = fmaf(nrm, w[3], x);
                // gelu (tanh approx, sigmoid form)
                float q = fmaf(x * x, 0.044715f, 1.0f);
                float e = __builtin_amdgcn_exp2f((-2.3022082f * x) * q);
                hv[j]   = x * __builtin_amdgcn_rcpf(1.0f + e);
            }
            unsigned up0 = cvt_pk_bf16(hv[0], hv[1]);
            unsigned up1 = cvt_pk_bf16(hv[2], hv[3]);
            unsigned up2 = cvt_pk_bf16(hv[4], hv[5]);
            unsigned up3 = cvt_pk_bf16(hv[6], hv[7]);
            __attribute__((ext_vector_type(4))) unsigned up = {up0, up1, up2, up3};
            const bf16x8 av = __builtin_bit_cast(bf16x8, up);
            acc = __builtin_amdgcn_mfma_f32_16x16x32_bf16(Af[0][kc], av, acc, 0, 0, 0);
            acc = __builtin_amdgcn_mfma_f32_16x16x32_bf16(Af[1][kc], av, acc, 0, 0, 0);
        }

        // stash to transpose buffer: logical (bl, a=col, i=g*4..g*4+3)
        const int base = bl * 306 + col * 18 + g * 4;
        *reinterpret_cast<f32x2*>(&wbuf[base])     = (f32x2){acc[0], acc[1]};
        *reinterpret_cast<f32x2*>(&wbuf[base + 2]) = (f32x2){acc[2], acc[3]};
    }

    // flush: per a-row, lanes cover (b'=lane>>3, i=(lane&7)*2 .. +1)
    // -> global addr offset = lane*2 floats: one contiguous 512B store
    const int bp = lane >> 3;
    const int ip = lane & 7;
    #pragma unroll
    for (int ar = 0; ar < 16; ++ar) {
        const f32x2 v = *reinterpret_cast<const f32x2*>(&wbuf[bp * 306 + ar * 18 + ip * 2]);
        float* op = out + (((size_t)(z * NQ + a0 + ar)) * NQ + bq) * CO + lane * 2;
        *reinterpret_cast<f32x2*>(op) = v;
    }
}

// ---------------------------------------------------------------------------
// Fallback (round-10 proven, 25.3 us) if ws_size too small.
// ---------------------------------------------------------------------------
__global__ __launch_bounds__(256, 4) void fused_mfma_kernel(
    const float* __restrict__ features, const float* __restrict__ geometry,
    const float* __restrict__ W1, const float* __restrict__ b1,
    const float* __restrict__ W2, const float* __restrict__ b2,
    float* __restrict__ out)
{
    __shared__ __attribute__((aligned(16))) unsigned short Mhi[CO * HIDN];
    __shared__ __attribute__((aligned(16))) unsigned short Mlo[CO * HIDN];
    __shared__ __attribute__((aligned(16))) float W1_sm[HIDN * 4];
    __shared__ float b1_sm[HIDN];
    __shared__ float c_sm[CO];
    __shared__ float f_sm[CI];

    const int bid = blockIdx.x;
    const int zb  = bid >> 1;
    const int a0  = (bid & 1) << 8;
    const int z   = zb >> 9;
    const int b   = zb & 511;
    const int tid = threadIdx.x;

    W1_sm[tid] = W1[tid];
    if (tid < HIDN) b1_sm[tid] = b1[tid];
    if (tid < CI)   f_sm[tid]  = features[zb * CI + tid];
    __syncthreads();

    const int wv    = tid >> 6;
    const int lane  = tid & 63;
    const int col   = lane & 15;
    const int g     = lane >> 4;
    const int abase = a0 + wv * 64;

    const float gbx = geometry[(z * NQ + b) * 3 + 0];
    const float gby = geometry[(z * NQ + b) * 3 + 1];
    const float gbz = geometry[(z * NQ + b) * 3 + 2];
    float rel[4][4];
    #pragma unroll
    for (int t = 0; t < 4; ++t) {
        const float* ga = geometry + (size_t)(z * NQ + abase + t * 16 + col) * 3;
        float rx = gbx - ga[0], ry = gby - ga[1], rz = gbz - ga[2];
        rel[t][0] = rx; rel[t][1] = ry; rel[t][2] = rz;
        rel[t][3] = sqrtf(fmaf(rx, rx, fmaf(ry, ry, rz * rz)) + 1e-12f);
    }

    {
        const int i  = tid >> 4;
        const int k4 = (tid & 15) << 2;
        f32x4 m = {0.f, 0.f, 0.f, 0.f};
        #pragma unroll
        for (int j = 0; j < CI; ++j) {
            const f32x4 w2 = *reinterpret_cast<const f32x4*>(&W2[(i * CI + j) * HIDN + k4]);
            const float fj = f_sm[j];
            #pragma unroll
            for (int p = 0; p < 4; ++p) m[p] = fmaf(fj, w2[p], m[p]);
        }
        const unsigned h0 = cvt_pk_bf16(m[0], m[1]);
        const unsigned h1 = cvt_pk_bf16(m[2], m[3]);
        const float f0 = __builtin_bit_cast(float, h0 << 16);
        const float f1 = __builtin_bit_cast(float, h0 & 0xffff0000u);
        const float f2 = __builtin_bit_cast(float, h1 << 16);
        const float f3 = __builtin_bit_cast(float, h1 & 0xffff0000u);
        const unsigned l0 = cvt_pk_bf16(m[0] - f0, m[1] - f1);
        const unsigned l1 = cvt_pk_bf16(m[2] - f2, m[3] - f3);
        const int bir = (k4 << 1) ^ ((i & 7) << 4);
        typedef __attribute__((ext_vector_type(2))) unsigned u32x2;
        *reinterpret_cast<u32x2*>(reinterpret_cast<char*>(Mhi) + i * 128 + bir) = (u32x2){h0, h1};
        *reinterpret_cast<u32x2*>(reinterpret_cast<char*>(Mlo) + i * 128 + bir) = (u32x2){l0, l1};
    }
    if (tid < CO) {
        float acc = 0.f;
        #pragma unroll
        for (int j = 0; j < CI; ++j)
            acc = fmaf(f_sm[j], b2[tid * CI + j], acc);
        c_sm[tid] = acc;
    }
    __syncthreads();

    bf16x8 Af[2][2];
    #pragma unroll
    for (int kc = 0; kc < 2; ++kc) {
        const int bir = (kc * 64 + g * 16) ^ ((col & 7) << 4);
        Af[0][kc] = *reinterpret_cast<const bf16x8*>(reinterpret_cast<const char*>(Mhi) + col * 128 + bir);
        Af[1][kc] = *reinterpret_cast<const bf16x8*>(reinterpret_cast<const char*>(Mlo) + col * 128 + bir);
    }

    f32x4 cin;
    #pragma unroll
    for (int r = 0; r < 4; ++r) cin[r] = c_sm[g * 4 + r];
    f32x4 acc[4];
    #pragma unroll
    for (int t = 0; t < 4; ++t) acc[t] = cin;

    #pragma unroll
    for (int kc = 0; kc < 2; ++kc) {
        f32x4 w[8]; float bbias[8];
        #pragma unroll
        for (int j = 0; j < 8; ++j) {
            const int h = kc * 32 + g * 8 + j;
            w[j]     = *reinterpret_cast<const f32x4*>(&W1_sm[h * 4]);
            bbias[j] = b1_sm[h];
        }
        #pragma unroll
        for (int t = 0; t < 4; ++t) {
            float hv[8];
            #pragma unroll
            for (int j = 0; j < 8; ++j) {
                float x = bbias[j];
                x = fmaf(rel[t][0], w[j][0], x);
                x = fmaf(rel[t][1], w[j][1], x);
                x = fmaf(rel[t][2], w[j][2], x);
                x = fmaf(rel[t][3], w[j][3], x);
                float q = fmaf(x * x, 0.044715f, 1.0f);
                float e = __builtin_amdgcn_exp2f((-2.3022082f * x) * q);
                hv[j]   = x * __builtin_amdgcn_rcpf(1.0f + e);
            }
            typedef __attribute__((ext_vector_type(4))) unsigned u32x4;
            u32x4 up;
            #pragma unroll
            for (int p = 0; p < 4; ++p)
                up[p] = cvt_pk_bf16(hv[2 * p], hv[2 * p + 1]);
            const bf16x8 av = __builtin_bit_cast(bf16x8, up);
            acc[t] = __builtin_amdgcn_mfma_f32_16x16x32_bf16(Af[0][kc], av, acc[t], 0, 0, 0);
            acc[t] = __builtin_amdgcn_mfma_f32_16x16x32_bf16(Af[1][kc], av, acc[t], 0, 0, 0);
        }
    }

    #pragma unroll
    for (int t = 0; t < 4; ++t) {
        float* op = out + (((size_t)(z * NQ + abase + t * 16 + col)) * NQ + b) * CO + g * 4;
        *reinterpret_cast<f32x4*>(op) = acc[t];
    }
}

extern "C" void kernel_launch(void* const* d_in, const int* in_sizes, int n_in,
                              void* d_out, int out_size, void* d_ws, size_t ws_size,
                              hipStream_t stream) {
    const float* features = (const float*)d_in[0];
    const float* geometry = (const float*)d_in[1];
    const float* W1       = (const float*)d_in[2];
    const float* b1       = (const float*)d_in[3];
    const float* W2       = (const float*)d_in[4];
    const float* b2       = (const float*)d_in[5];
    float* out = (float*)d_out;

    const size_t needM = (size_t)1024 * 2048 * sizeof(unsigned short); // 4 MB
    const size_t needC = (size_t)1024 * CO * sizeof(float);            // 64 KB
    if (ws_size >= needM + needC) {
        unsigned short* Mbf = (unsigned short*)d_ws;
        float* Cws = (float*)((char*)d_ws + needM);
        compute_M_kernel<<<1024, 256, 0, stream>>>(features, W2, b2, Mbf, Cws);
        apply_transpose_kernel<<<512, 512, 0, stream>>>(
            geometry, W1, b1, Mbf, Cws, out);
    } else {
        fused_mfma_kernel<<<2048, 256, 0, stream>>>(
            features, geometry, W1, b1, W2, b2, out);
    }
}

// Round 12
// 29.636 us; speedup vs baseline: 1.3920x; 1.3920x over previous
//
#include <hip/hip_runtime.h>

// B=2, N=512, C_IN=16, C_OUT=16, HID=64
#define NQ   512
#define CI   16
#define CO   16
#define HIDN 64

typedef __attribute__((ext_vector_type(8))) short bf16x8;
typedef __attribute__((ext_vector_type(4))) float f32x4;
typedef __attribute__((ext_vector_type(2))) unsigned u32x2;
typedef __attribute__((ext_vector_type(4))) unsigned u32x4;

// packed bf16 convert: low16 = bf16(a), high16 = bf16(b)
__device__ __forceinline__ unsigned cvt_pk_bf16(float a, float b) {
    unsigned r;
    asm("v_cvt_pk_bf16_f32 %0, %1, %2" : "=v"(r) : "v"(a), "v"(b));
    return r;
}

// ---------------------------------------------------------------------------
// 1024 blocks = z(2) x b-pair(256) x a-half(2); 256 threads = 4 waves.
// Exactly ONE grid generation: 4 blocks/CU x 4 waves = 4 waves/SIMD.
//
// Stage A (once per block, ONE barrier): M for BOTH b's -> bf16 hi/lo planes
// in LDS (r10-proven swizzle: byte ^= (i&7)<<4 within 128B rows); W2 tile
// loaded once, reused for both b's. f via uniform scalar loads (no LDS).
//
// Main: loop bb=0,1 over the two b's — each iteration is the r10-proven
// compute (A-frag ds_read_b128, 64 gelu in B-frag layout, 16 MFMA hi/lo,
// 4 contiguous dwordx4 stores). Two phases per block keep pipes fed.
// ---------------------------------------------------------------------------
__global__ __launch_bounds__(256, 4) void fused_mfma2_kernel(
    const float* __restrict__ features,   // [1024,16]
    const float* __restrict__ geometry,   // [1024,3]
    const float* __restrict__ W1,         // [64,4]
    const float* __restrict__ b1,         // [64]
    const float* __restrict__ W2,         // [256,64]
    const float* __restrict__ b2,         // [256]
    float* __restrict__ out)              // [2,512,512,16]
{
    __shared__ __attribute__((aligned(16))) unsigned short Mhi[2][CO * HIDN];
    __shared__ __attribute__((aligned(16))) unsigned short Mlo[2][CO * HIDN];
    __shared__ __attribute__((aligned(16))) float W1_sm[HIDN * 4];
    __shared__ float b1_sm[HIDN];
    __shared__ float c_sm[2][CO];

    const int bid  = blockIdx.x;
    const int z    = bid >> 9;
    const int rest = bid & 511;
    const int b0   = (rest >> 1) << 1;   // even b of the pair
    const int a0   = (rest & 1) << 8;    // a-half
    const int tid  = threadIdx.x;

    W1_sm[tid] = W1[tid];                // 256 floats
    if (tid < HIDN) b1_sm[tid] = b1[tid];

    // ---- stage A: M (f32) for both b's -> bf16 hi/lo planes, swizzled ----
    {
        const int i  = tid >> 4;         // 0..15
        const int k4 = (tid & 15) << 2;  // 0,4,..,60
        f32x4 m0 = {0.f, 0.f, 0.f, 0.f};
        f32x4 m1 = {0.f, 0.f, 0.f, 0.f};
        #pragma unroll
        for (int j = 0; j < CI; ++j) {
            const f32x4 w2 = *reinterpret_cast<const f32x4*>(&W2[(i * CI + j) * HIDN + k4]);
            const float fj0 = features[(z * NQ + b0)     * CI + j];  // uniform -> s_load
            const float fj1 = features[(z * NQ + b0 + 1) * CI + j];  // uniform -> s_load
            #pragma unroll
            for (int p = 0; p < 4; ++p) {
                m0[p] = fmaf(fj0, w2[p], m0[p]);
                m1[p] = fmaf(fj1, w2[p], m1[p]);
            }
        }
        const int bir = (k4 << 1) ^ ((i & 7) << 4);   // swizzled byte-in-row
        #pragma unroll
        for (int bb = 0; bb < 2; ++bb) {
            const f32x4 m = bb ? m1 : m0;
            const unsigned h0 = cvt_pk_bf16(m[0], m[1]);
            const unsigned h1 = cvt_pk_bf16(m[2], m[3]);
            const float f0 = __builtin_bit_cast(float, h0 << 16);
            const float f1 = __builtin_bit_cast(float, h0 & 0xffff0000u);
            const float f2 = __builtin_bit_cast(float, h1 << 16);
            const float f3 = __builtin_bit_cast(float, h1 & 0xffff0000u);
            const unsigned l0 = cvt_pk_bf16(m[0] - f0, m[1] - f1);
            const unsigned l1 = cvt_pk_bf16(m[2] - f2, m[3] - f3);
            *reinterpret_cast<u32x2*>(reinterpret_cast<char*>(Mhi[bb]) + i * 128 + bir) = (u32x2){h0, h1};
            *reinterpret_cast<u32x2*>(reinterpret_cast<char*>(Mlo[bb]) + i * 128 + bir) = (u32x2){l0, l1};
        }
    }
    if (tid < 32) {
        const int bb = tid >> 4, i = tid & 15;
        float acc = 0.f;
        #pragma unroll
        for (int j = 0; j < CI; ++j)
            acc = fmaf(features[(z * NQ + b0 + bb) * CI + j], b2[i * CI + j], acc);
        c_sm[bb][i] = acc;
    }
    __syncthreads();   // the only barrier

    const int wv    = tid >> 6;
    const int lane  = tid & 63;
    const int col   = lane & 15;         // = i for A-frag, = a-offset for B-frag
    const int g     = lane >> 4;
    const int abase = a0 + wv * 64;

    #pragma unroll 1
    for (int bb = 0; bb < 2; ++bb) {
        const int b = b0 + bb;
        // wave-uniform b -> scalar loads
        const float gbx = geometry[(z * NQ + b) * 3 + 0];
        const float gby = geometry[(z * NQ + b) * 3 + 1];
        const float gbz = geometry[(z * NQ + b) * 3 + 2];

        // ---- A fragments: one ds_read_b128 per (part,kc) ----
        bf16x8 Af[2][2];   // [part][kc]
        #pragma unroll
        for (int kc = 0; kc < 2; ++kc) {
            const int bir = (kc * 64 + g * 16) ^ ((col & 7) << 4);
            Af[0][kc] = *reinterpret_cast<const bf16x8*>(reinterpret_cast<const char*>(Mhi[bb]) + col * 128 + bir);
            Af[1][kc] = *reinterpret_cast<const bf16x8*>(reinterpret_cast<const char*>(Mlo[bb]) + col * 128 + bir);
        }

        // ---- rel per tile (a = abase + t*16 + col); ga reloads are L1-hits ----
        float rel[4][4];
        #pragma unroll
        for (int t = 0; t < 4; ++t) {
            const float* ga = geometry + (size_t)(z * NQ + abase + t * 16 + col) * 3;
            const float rx = gbx - ga[0], ry = gby - ga[1], rz = gbz - ga[2];
            rel[t][0] = rx; rel[t][1] = ry; rel[t][2] = rz;
            rel[t][3] = sqrtf(fmaf(rx, rx, fmaf(ry, ry, rz * rz)) + 1e-12f);
        }

        // ---- accumulator init: lane (col,g) holds D^T rows i = g*4+r ----
        f32x4 cin;
        #pragma unroll
        for (int r = 0; r < 4; ++r) cin[r] = c_sm[bb][g * 4 + r];
        f32x4 acc[4];
        #pragma unroll
        for (int t = 0; t < 4; ++t) acc[t] = cin;

        // ---- main: hv (B-frag: n=a=col, k=g*8+j), 2 MFMAs (hi+lo) per (t,kc) ----
        #pragma unroll
        for (int kc = 0; kc < 2; ++kc) {
            f32x4 w[8]; float bbias[8];
            #pragma unroll
            for (int j = 0; j < 8; ++j) {
                const int h = kc * 32 + g * 8 + j;
                w[j]     = *reinterpret_cast<const f32x4*>(&W1_sm[h * 4]);  // broadcast LDS
                bbias[j] = b1_sm[h];
            }
            #pragma unroll
            for (int t = 0; t < 4; ++t) {
                float hv[8];
                #pragma unroll
                for (int j = 0; j < 8; ++j) {
                    float x = bbias[j];
                    x = fmaf(rel[t][0], w[j][0], x);
                    x = fmaf(rel[t][1], w[j][1], x);
                    x = fmaf(rel[t][2], w[j][2], x);
                    x = fmaf(rel[t][3], w[j][3], x);
                    // gelu (tanh approx, sigmoid form)
                    float q = fmaf(x * x, 0.044715f, 1.0f);
                    float e = __builtin_amdgcn_exp2f((-2.3022082f * x) * q);
                    hv[j]   = x * __builtin_amdgcn_rcpf(1.0f + e);
                }
                u32x4 up;
                #pragma unroll
                for (int p = 0; p < 4; ++p)
                    up[p] = cvt_pk_bf16(hv[2 * p], hv[2 * p + 1]);
                const bf16x8 av = __builtin_bit_cast(bf16x8, up);
                acc[t] = __builtin_amdgcn_mfma_f32_16x16x32_bf16(Af[0][kc], av, acc[t], 0, 0, 0);
                acc[t] = __builtin_amdgcn_mfma_f32_16x16x32_bf16(Af[1][kc], av, acc[t], 0, 0, 0);
            }
        }

        // ---- epilogue: row a = abase+t*16+col, cols i = g*4..g*4+3 ----
        #pragma unroll
        for (int t = 0; t < 4; ++t) {
            float* op = out + (((size_t)(z * NQ + abase + t * 16 + col)) * NQ + b) * CO + g * 4;
            *reinterpret_cast<f32x4*>(op) = acc[t];
        }
    }
}

extern "C" void kernel_launch(void* const* d_in, const int* in_sizes, int n_in,
                              void* d_out, int out_size, void* d_ws, size_t ws_size,
                              hipStream_t stream) {
    const float* features = (const float*)d_in[0];
    const float* geometry = (const float*)d_in[1];
    const float* W1       = (const float*)d_in[2];
    const float* b1       = (const float*)d_in[3];
    const float* W2       = (const float*)d_in[4];
    const float* b2       = (const float*)d_in[5];
    float* out = (float*)d_out;

    fused_mfma2_kernel<<<1024, 256, 0, stream>>>(
        features, geometry, W1, b1, W2, b2, out);
}